// Round 2
// baseline (250.488 us; speedup 1.0000x reference)
//
#include <hip/hip_runtime.h>
#include <math.h>

// SGC: K=2 hops of D^-1/2 (A+I) D^-1/2, then x@W+b, then log_softmax.
// N=100000, D=64, C=40, E=1600000.
//
// R10 (this round): build_csr was the hidden co-bottleneck (62 us, VALUBusy 7%,
// occupancy 11.6% -> latency-bound on the serial per-row insertion sort's
// dependent LDS chain). Replace it with parallel rank-and-place:
//  - scatter unsorted into lcsr (as before), pad rows with n,
//  - each row's entries get rank = #{v_j < v_i} + #{j<i: v_j == v_i} via
//    independent int4 LDS scans (latency-pipelined, no serial chain),
//  - write sorted entries DIRECTLY to global csr_col (copy-out phase deleted).
// Sorted multiset order is a pure function of the edge multiset -> CSR is
// bit-identical to the insertion-sort version; SpMM output unchanged.
//
// Carried from R9: degree-grouped perm scheduling, v_pk_add_f32 accumulate,
// LDS-transpose GEMV epilogue, __launch_bounds__(256,6) on SpMM kernels.

#define D_FEAT 64
#define NCLS 40
#define BROWS 512       // rows per bucket
#define BROWS_LOG 9
#define BINCAP 10240    // per-bucket edge capacity (mean 8192, sd ~90)
#define CSRCAP 12288    // per-bucket csr capacity (max padded = 10240+3*512 = 11776)
#define EPT 25          // edges per thread in bin_edges (250 blocks)

typedef float v2f __attribute__((ext_vector_type(2)));

__device__ __forceinline__ unsigned pack_bf16_2(float lo, float hi) {
    unsigned ulo = __float_as_uint(lo);
    unsigned uhi = __float_as_uint(hi);
    ulo = (ulo + 0x7fffu + ((ulo >> 16) & 1u)) >> 16;           // RNE
    uhi = (uhi + 0x7fffu + ((uhi >> 16) & 1u)) & 0xffff0000u;   // RNE
    return uhi | ulo;
}

// packed-accumulate one dword (2 bf16 features) into a float2 accumulator
__device__ __forceinline__ void acc2p(unsigned u, v2f& a) {
    v2f v;
    v.x = __uint_as_float(u << 16);
    v.y = __uint_as_float(u & 0xffff0000u);
    a += v;   // <2 x float> fadd -> v_pk_add_f32
}

__global__ void zero_cursors_kernel(int* __restrict__ cur, int nb) {
    int i = blockIdx.x * blockDim.x + threadIdx.x;
    if (i < nb) cur[i] = 0;
}

// Bin edges into per-bucket regions. Packed entry: (row&511)<<17 | col.
// (Requires n <= 131072 so col fits 17 bits; n = 100000 here.)
__global__ __launch_bounds__(256) void bin_edges_kernel(const int* __restrict__ rows,
                                                        const int* __restrict__ cols,
                                                        int* __restrict__ bucket_cursor,
                                                        unsigned* __restrict__ bins,
                                                        int e, int nb) {
    __shared__ int cnt[512];
    for (int i = threadIdx.x; i < nb; i += 256) cnt[i] = 0;
    __syncthreads();
    int base = blockIdx.x * (256 * EPT) + threadIdx.x;
    int rr[EPT], cc[EPT];
#pragma unroll
    for (int k = 0; k < EPT; k++) {
        int idx = base + k * 256;
        if (idx < e) { rr[k] = rows[idx]; cc[k] = cols[idx]; }
        else { rr[k] = -1; cc[k] = 0; }
    }
#pragma unroll
    for (int k = 0; k < EPT; k++)
        if (rr[k] >= 0) atomicAdd(&cnt[rr[k] >> BROWS_LOG], 1);
    __syncthreads();
    for (int i = threadIdx.x; i < nb; i += 256) {
        int c = cnt[i];
        cnt[i] = (c > 0) ? atomicAdd(&bucket_cursor[i], c) : 0;  // global base
    }
    __syncthreads();
#pragma unroll
    for (int k = 0; k < EPT; k++) {
        if (rr[k] >= 0) {
            int b = rr[k] >> BROWS_LOG;
            int pos = atomicAdd(&cnt[b], 1);  // absolute pos within bucket
            bins[(size_t)b * BINCAP + pos] =
                ((unsigned)(rr[k] & (BROWS - 1)) << 17) | (unsigned)cc[k];
        }
    }
}

// One 512-thread block per bucket, all staged in LDS. Emits sorted,
// dummy-padded CSR (deterministic) + row_info + dis + degree-grouped perm.
// Sort = parallel rank-and-place (independent LDS loads, no serial chain).
__global__ __launch_bounds__(512) void build_csr_kernel(const unsigned* __restrict__ bins,
                                                        const int* __restrict__ bucket_cursor,
                                                        int* __restrict__ csr_col,
                                                        uint2* __restrict__ row_info,
                                                        float* __restrict__ dis,
                                                        int* __restrict__ perm, int n) {
    __shared__ int cnt[512];
    __shared__ int sm[512];
    __shared__ int cur[512];
    __shared__ int lcsr[CSRCAP];  // 48 KB; total static LDS = 54 KB
    int b = blockIdx.x;
    int tid = threadIdx.x;
    int m = bucket_cursor[b];
    cnt[tid] = 0;
    __syncthreads();
    const unsigned* bp = bins + (size_t)b * BINCAP;
    for (int i = tid; i < m; i += 512) atomicAdd(&cnt[bp[i] >> 17], 1);
    __syncthreads();
    int c = cnt[tid];
    int padded = (c + 3) & ~3;
    int r = b * BROWS + tid;
    if (r < n) dis[r] = rsqrtf(1.0f + (float)c);
    sm[tid] = padded;
    __syncthreads();
    for (int off = 1; off < 512; off <<= 1) {
        int t = (tid >= off) ? sm[tid - off] : 0;
        __syncthreads();
        sm[tid] += t;
        __syncthreads();
    }
    int off0 = sm[tid] - padded;  // exclusive scan
    cur[tid] = off0;
    if (r < n) row_info[r] = make_uint2((unsigned)(b * CSRCAP + off0), (unsigned)padded);
    __syncthreads();
    for (int i = tid; i < m; i += 512) {
        unsigned u = bp[i];
        int pos = atomicAdd(&cur[u >> 17], 1);
        lcsr[pos] = (int)(u & 0x1FFFFu);
    }
    __syncthreads();

    // ---- parallel rank-and-place (deterministic: sorted multiset order) ----
    // Pad own row's tail with n (so the int4 rank scan needs no bound checks;
    // n compares strictly greater than every real col < n).
    int gb = b * CSRCAP + off0;
    if (r < n) {
        for (int j = c; j < padded; j++) lcsr[off0 + j] = n;
        // pads written by the same thread that reads them below: no barrier.
        const int4* l4 = (const int4*)lcsr;
        int v0 = off0 >> 2;        // off0 is a multiple of 4 -> aligned
        int nv = padded >> 2;
        for (int i = 0; i < c; i++) {
            int vi = lcsr[off0 + i];
            int rank = 0;
            for (int j4 = 0; j4 < nv; j4++) {
                int4 w = l4[v0 + j4];
                int jb = j4 << 2;
                rank += (w.x < vi) || (w.x == vi && (jb    ) < i);
                rank += (w.y < vi) || (w.y == vi && (jb + 1) < i);
                rank += (w.z < vi) || (w.z == vi && (jb + 2) < i);
                rank += (w.w < vi) || (w.w == vi && (jb + 3) < i);
            }
            csr_col[gb + rank] = vi;   // sorted position, straight to global
        }
        for (int j = c; j < padded; j++) csr_col[gb + j] = n;  // dummy pad slots
    }

    // ---- degree-grouped perm: counting sort of bucket rows by padded len ----
    // (rank order within a bin is nondeterministic, but output is per-row
    //  independent of wave assignment -> bit-identical results.)
    // Only touches cnt/sm/cur, which the rank phase above does not read.
    __syncthreads();
    if (tid < 64) cnt[tid] = 0;
    __syncthreads();
    int bin = min(padded >> 2, 63);
    if (r < n) atomicAdd(&cnt[bin], 1);
    __syncthreads();
    if (tid < 64) sm[tid] = cnt[tid];
    __syncthreads();
    for (int off = 1; off < 64; off <<= 1) {
        int t = (tid >= off && tid < 64) ? sm[tid - off] : 0;
        __syncthreads();
        if (tid < 64) sm[tid] += t;
        __syncthreads();
    }
    if (tid < 64) cur[tid] = sm[tid] - cnt[tid];  // exclusive bin base
    __syncthreads();
    if (r < n) {
        int rank = atomicAdd(&cur[bin], 1);
        perm[b * BROWS + rank] = r;
    } else {
        perm[b * BROWS + tid] = -1;  // tid >= valid-count exactly when r >= n
    }
}

// xs0[i] = bf16(dis[i] * x[i,:]) packed 2/dword; dummy rows (n) of BOTH xs
// arrays zeroed (pad slots gather row n).
__global__ void scale_x_kernel(const float* __restrict__ x, const float* __restrict__ dis,
                               unsigned* __restrict__ xs0, unsigned* __restrict__ xs1, int n) {
    int i = blockIdx.x * blockDim.x + threadIdx.x;  // over (n+1)*32 dwords
    int total = (n + 1) * (D_FEAT / 2);
    if (i >= total) return;
    int node = i >> 5;
    if (node < n) {
        float s = dis[node];
        float2 v = ((const float2*)x)[i];
        xs0[i] = pack_bf16_2(s * v.x, s * v.y);
    } else {
        xs0[i] = 0u;
        xs1[i] = 0u;  // dummy row of hop-1 output
    }
}

// Gather 16 slots (4 predicated groups of 4) for one quarter's row chunk.
// Accumulates into v2f h01 (features 4ql,4ql+1) and h23 (4ql+2,4ql+3).
#define GATHER16(cp, xs_in, ql, base, len)                                  \
    uint2 u0 = make_uint2(0u, 0u), u1 = u0, u2 = u0, u3 = u0;               \
    uint2 u4 = u0, u5 = u0, u6 = u0, u7 = u0;                               \
    uint2 u8 = u0, u9 = u0, u10 = u0, u11 = u0;                             \
    uint2 u12 = u0, u13 = u0, u14 = u0, u15 = u0;                           \
    if (base < len) {                                                       \
        uint4 cv = cp[(base >> 2) + 0];                                     \
        u0 = xs_in[cv.x * 16 + ql]; u1 = xs_in[cv.y * 16 + ql];             \
        u2 = xs_in[cv.z * 16 + ql]; u3 = xs_in[cv.w * 16 + ql];             \
    }                                                                       \
    if (base + 4 < len) {                                                   \
        uint4 cv = cp[(base >> 2) + 1];                                     \
        u4 = xs_in[cv.x * 16 + ql]; u5 = xs_in[cv.y * 16 + ql];             \
        u6 = xs_in[cv.z * 16 + ql]; u7 = xs_in[cv.w * 16 + ql];             \
    }                                                                       \
    if (base + 8 < len) {                                                   \
        uint4 cv = cp[(base >> 2) + 2];                                     \
        u8 = xs_in[cv.x * 16 + ql]; u9 = xs_in[cv.y * 16 + ql];             \
        u10 = xs_in[cv.z * 16 + ql]; u11 = xs_in[cv.w * 16 + ql];           \
    }                                                                       \
    if (base + 12 < len) {                                                  \
        uint4 cv = cp[(base >> 2) + 3];                                     \
        u12 = xs_in[cv.x * 16 + ql]; u13 = xs_in[cv.y * 16 + ql];           \
        u14 = xs_in[cv.z * 16 + ql]; u15 = xs_in[cv.w * 16 + ql];           \
    }                                                                       \
    acc2p(u0.x, h01); acc2p(u0.y, h23);                                     \
    acc2p(u1.x, h01); acc2p(u1.y, h23);                                     \
    acc2p(u2.x, h01); acc2p(u2.y, h23);                                     \
    acc2p(u3.x, h01); acc2p(u3.y, h23);                                     \
    acc2p(u4.x, h01); acc2p(u4.y, h23);                                     \
    acc2p(u5.x, h01); acc2p(u5.y, h23);                                     \
    acc2p(u6.x, h01); acc2p(u6.y, h23);                                     \
    acc2p(u7.x, h01); acc2p(u7.y, h23);                                     \
    acc2p(u8.x, h01); acc2p(u8.y, h23);                                     \
    acc2p(u9.x, h01); acc2p(u9.y, h23);                                     \
    acc2p(u10.x, h01); acc2p(u10.y, h23);                                   \
    acc2p(u11.x, h01); acc2p(u11.y, h23);                                   \
    acc2p(u12.x, h01); acc2p(u12.y, h23);                                   \
    acc2p(u13.x, h01); acc2p(u13.y, h23);                                   \
    acc2p(u14.x, h01); acc2p(u14.y, h23);                                   \
    acc2p(u15.x, h01); acc2p(u15.y, h23);

// Hop 1: xs1[r,:] = bf16( dis[r]^2 * ( xs0[r,:] + sum_c xs0[c,:] ) ).
// Wave w processes rows perm[4w+q]; lane (q,ql) holds features 4ql..4ql+3.
__global__ __launch_bounds__(256, 6) void spmm_hop1_kernel(const uint2* __restrict__ xs_in,
                                                           uint2* __restrict__ xs_out,
                                                           const int* __restrict__ perm,
                                                           const uint2* __restrict__ row_info,
                                                           const int* __restrict__ csr_col,
                                                           const float* __restrict__ dis,
                                                           int n, int nperm) {
    int wave = (blockIdx.x * blockDim.x + threadIdx.x) >> 6;
    int lane = threadIdx.x & 63;
    int q = lane >> 4, ql = lane & 15;
    int pidx = wave * 4 + q;
    int r = (pidx < nperm) ? perm[pidx] : -1;
    bool valid = (r >= 0);
    int s = 0, len = 0;
    if (valid) { uint2 info = row_info[r]; s = (int)info.x; len = (int)info.y; }
    int maxlen = len;
    maxlen = max(maxlen, __shfl_xor(maxlen, 16, 64));
    maxlen = max(maxlen, __shfl_xor(maxlen, 32, 64));

    v2f h01 = {0.f, 0.f}, h23 = {0.f, 0.f};
    const uint4* cp = (const uint4*)(csr_col + s);  // s is a multiple of 4
    for (int base = 0; base < maxlen; base += 16) {
        GATHER16(cp, xs_in, ql, base, len)
    }
    if (valid) {
        uint2 us = xs_in[r * 16 + ql];  // self term
        acc2p(us.x, h01); acc2p(us.y, h23);
        float dr = dis[r];
        float dr2 = dr * dr;
        xs_out[r * 16 + ql] = make_uint2(pack_bf16_2(dr2 * h01.x, dr2 * h01.y),
                                         pack_bf16_2(dr2 * h23.x, dr2 * h23.y));
    }
}

// Hop 2 fused with logits + log_softmax. h2[r,:] = dis[r]*(xs1[r,:]+sum_c xs1[c,:]).
// GEMV: per-wave LDS transpose of h (hl, padded) + transposed padded Wt;
// lane ql covers classes ql, ql+16, (ql<8) ql+32. Inner loop is broadcast
// ds_read_b128 + FMA only (no shfl, no scalar W reads).
__global__ __launch_bounds__(256, 6) void spmm_logits_kernel(const uint2* __restrict__ xs_in,
                                                             const int* __restrict__ perm,
                                                             const uint2* __restrict__ row_info,
                                                             const int* __restrict__ csr_col,
                                                             const float* __restrict__ dis,
                                                             const float* __restrict__ W,
                                                             const float* __restrict__ b,
                                                             float* __restrict__ out,
                                                             int n, int nperm) {
    __shared__ float Wt[NCLS][D_FEAT + 4];  // transposed, padded: 2-lane/bank max
    __shared__ float bl[NCLS];
    __shared__ float hl[16][D_FEAT + 4];    // 4 waves x 4 rows; padded rows
    for (int i = threadIdx.x; i < D_FEAT * NCLS; i += 256) {
        int d = i / NCLS, cc = i - d * NCLS;
        Wt[cc][d] = W[i];
    }
    for (int i = threadIdx.x; i < NCLS; i += 256) bl[i] = b[i];
    __syncthreads();

    int wave = (blockIdx.x * blockDim.x + threadIdx.x) >> 6;
    int lane = threadIdx.x & 63;
    int q = lane >> 4, ql = lane & 15;
    int pidx = wave * 4 + q;
    int r = (pidx < nperm) ? perm[pidx] : -1;
    bool valid = (r >= 0);
    int s = 0, len = 0;
    if (valid) { uint2 info = row_info[r]; s = (int)info.x; len = (int)info.y; }
    int maxlen = len;
    maxlen = max(maxlen, __shfl_xor(maxlen, 16, 64));
    maxlen = max(maxlen, __shfl_xor(maxlen, 32, 64));

    v2f h01 = {0.f, 0.f}, h23 = {0.f, 0.f};
    const uint4* cp = (const uint4*)(csr_col + s);
    for (int base = 0; base < maxlen; base += 16) {
        GATHER16(cp, xs_in, ql, base, len)
    }

    float y0, y1, y2;
    int c0 = ql, c1 = ql + 16;
    int c2 = (ql < 8) ? (ql + 32) : ql;  // dup addr -> broadcast, no conflict
    {
        uint2 us = valid ? xs_in[r * 16 + ql] : make_uint2(0u, 0u);  // self term
        acc2p(us.x, h01); acc2p(us.y, h23);
        float dr = valid ? dis[r] : 0.f;
        float h0 = h01.x * dr, h1 = h01.y * dr, h2 = h23.x * dr, h3 = h23.y * dr;

        // per-wave transpose: row's 64 features laid out in hl[rowslot][*].
        // Same-wave produce->consume via LDS (lockstep; compiler inserts
        // lgkmcnt ordering for may-alias LDS ops) -- no barrier needed.
        int rowslot = ((threadIdx.x >> 6) << 2) + q;
        *(float4*)&hl[rowslot][ql * 4] = make_float4(h0, h1, h2, h3);

        y0 = bl[c0]; y1 = bl[c1]; y2 = bl[c2];
#pragma unroll
        for (int g = 0; g < 16; g++) {
            float4 hv = *(const float4*)&hl[rowslot][g * 4];   // quarter-broadcast
            float4 w0 = *(const float4*)&Wt[c0][g * 4];
            float4 w1 = *(const float4*)&Wt[c1][g * 4];
            float4 w2 = *(const float4*)&Wt[c2][g * 4];
            y0 += hv.x * w0.x + hv.y * w0.y + hv.z * w0.z + hv.w * w0.w;
            y1 += hv.x * w1.x + hv.y * w1.y + hv.z * w1.z + hv.w * w1.w;
            y2 += hv.x * w2.x + hv.y * w2.y + hv.z * w2.z + hv.w * w2.w;
        }
    }

    bool has3 = (ql < 8);
    float m = fmaxf(y0, y1);
    if (has3) m = fmaxf(m, y2);
#pragma unroll
    for (int o = 8; o > 0; o >>= 1) m = fmaxf(m, __shfl_xor(m, o, 64));
    float sm = __expf(y0 - m) + __expf(y1 - m) + (has3 ? __expf(y2 - m) : 0.f);
#pragma unroll
    for (int o = 8; o > 0; o >>= 1) sm += __shfl_xor(sm, o, 64);
    float lse = m + __logf(sm);

    if (valid) {
        float* op = out + (long long)r * NCLS;
        op[ql] = y0 - lse;
        op[ql + 16] = y1 - lse;
        if (has3) op[ql + 32] = y2 - lse;
    }
}

extern "C" void kernel_launch(void* const* d_in, const int* in_sizes, int n_in,
                              void* d_out, int out_size, void* d_ws, size_t ws_size,
                              hipStream_t stream) {
    const float* x  = (const float*)d_in[0];
    const int*   ei = (const int*)d_in[1];   // [2, E] flat: rows then cols (int32)
    const float* W  = (const float*)d_in[2]; // [64, 40]
    const float* b  = (const float*)d_in[3]; // [40]
    float* out = (float*)d_out;

    const int n = in_sizes[0] / D_FEAT;      // 100000
    const int e = in_sizes[1] / 2;           // 1600000
    const int nb = (n + BROWS - 1) / BROWS;  // 196

    const int* rows = ei;
    const int* cols = ei + e;

    // ws layout (int units, segments aligned):
    //   bucket_cursor[nb] | dis[n] | row_info[n] (uint2) | perm[nb*512] |
    //   bins[nb*BINCAP] | csr_col[nb*CSRCAP] | xs0 | xs1       (~45 MB)
    size_t na = ((size_t)n + 256) & ~(size_t)255;
    size_t npm = (size_t)nb * BROWS;         // multiple of 512
    int*      bucket_cursor = (int*)d_ws;
    float*    dis           = (float*)(bucket_cursor + 256);
    uint2*    row_info      = (uint2*)(dis + na);
    int*      perm          = (int*)(row_info + na);
    unsigned* bins          = (unsigned*)(perm + npm);
    int*      csr_col       = (int*)(bins + (size_t)nb * BINCAP);
    unsigned* xs0           = (unsigned*)(csr_col + (size_t)nb * CSRCAP);
    unsigned* xs1           = xs0 + (size_t)(n + 1) * (D_FEAT / 2);

    const int BS = 256;

    zero_cursors_kernel<<<1, 256, 0, stream>>>(bucket_cursor, nb);
    {
        int blocks = (e + BS * EPT - 1) / (BS * EPT);  // 250
        bin_edges_kernel<<<blocks, BS, 0, stream>>>(rows, cols, bucket_cursor, bins, e, nb);
    }
    build_csr_kernel<<<nb, 512, 0, stream>>>(bins, bucket_cursor, csr_col, row_info, dis,
                                             perm, n);
    {
        int tot = (n + 1) * (D_FEAT / 2);
        scale_x_kernel<<<(tot + BS - 1) / BS, BS, 0, stream>>>(x, dis, xs0, xs1, n);
    }

    int nperm = (int)npm;                    // nb*512 perm slots
    int nwaves = nperm / 4;                  // 4 rows per wave
    int blocks = (nwaves * 64 + BS - 1) / BS;
    spmm_hop1_kernel<<<blocks, BS, 0, stream>>>((const uint2*)xs0, (uint2*)xs1, perm,
                                                row_info, csr_col, dis, n, nperm);
    spmm_logits_kernel<<<blocks, BS, 0, stream>>>((const uint2*)xs1, perm, row_info, csr_col,
                                                  dis, W, b, out, n, nperm);
}

// Round 3
// 211.768 us; speedup vs baseline: 1.1828x; 1.1828x over previous
//
#include <hip/hip_runtime.h>
#include <math.h>

// SGC: K=2 hops of D^-1/2 (A+I) D^-1/2, then x@W+b, then log_softmax.
// N=100000, D=64, C=40, E=1600000.
//
// R11 (this round): R10 post-mortem showed ANY O(row^2) sort inside build_csr
// (196 blocks, ~2 waves/SIMD) is latency-doomed. So:
//  - build_csr reverts to cheap streaming phases only: count, scan, scatter,
//    pad, int4 copy-out, perm. No sort.
//  - NEW sort_rows_kernel: one HALF-WAVE (32 lanes) per row, bitonic network
//    via __shfl_xor (15 steps; 64-lane path for padded in (32,64], serial
//    fallback beyond -- unreachable for Poisson(16) degrees). 50K independent
//    waves -> fully latency-hidden. Sorted multiset order is unique -> CSR is
//    bit-identical to the insertion-sort version; output unchanged.
//
// Carried from R9: degree-grouped perm scheduling, v_pk_add_f32 accumulate,
// LDS-transpose GEMV epilogue, __launch_bounds__(256,6) on SpMM kernels.

#define D_FEAT 64
#define NCLS 40
#define BROWS 512       // rows per bucket
#define BROWS_LOG 9
#define BINCAP 10240    // per-bucket edge capacity (mean 8192, sd ~90)
#define CSRCAP 12288    // per-bucket csr capacity (max padded = 10240+3*512 = 11776)
#define EPT 25          // edges per thread in bin_edges (250 blocks)

typedef float v2f __attribute__((ext_vector_type(2)));

__device__ __forceinline__ unsigned pack_bf16_2(float lo, float hi) {
    unsigned ulo = __float_as_uint(lo);
    unsigned uhi = __float_as_uint(hi);
    ulo = (ulo + 0x7fffu + ((ulo >> 16) & 1u)) >> 16;           // RNE
    uhi = (uhi + 0x7fffu + ((uhi >> 16) & 1u)) & 0xffff0000u;   // RNE
    return uhi | ulo;
}

// packed-accumulate one dword (2 bf16 features) into a float2 accumulator
__device__ __forceinline__ void acc2p(unsigned u, v2f& a) {
    v2f v;
    v.x = __uint_as_float(u << 16);
    v.y = __uint_as_float(u & 0xffff0000u);
    a += v;   // <2 x float> fadd -> v_pk_add_f32
}

__global__ void zero_cursors_kernel(int* __restrict__ cur, int nb) {
    int i = blockIdx.x * blockDim.x + threadIdx.x;
    if (i < nb) cur[i] = 0;
}

// Bin edges into per-bucket regions. Packed entry: (row&511)<<17 | col.
// (Requires n <= 131072 so col fits 17 bits; n = 100000 here.)
__global__ __launch_bounds__(256) void bin_edges_kernel(const int* __restrict__ rows,
                                                        const int* __restrict__ cols,
                                                        int* __restrict__ bucket_cursor,
                                                        unsigned* __restrict__ bins,
                                                        int e, int nb) {
    __shared__ int cnt[512];
    for (int i = threadIdx.x; i < nb; i += 256) cnt[i] = 0;
    __syncthreads();
    int base = blockIdx.x * (256 * EPT) + threadIdx.x;
    int rr[EPT], cc[EPT];
#pragma unroll
    for (int k = 0; k < EPT; k++) {
        int idx = base + k * 256;
        if (idx < e) { rr[k] = rows[idx]; cc[k] = cols[idx]; }
        else { rr[k] = -1; cc[k] = 0; }
    }
#pragma unroll
    for (int k = 0; k < EPT; k++)
        if (rr[k] >= 0) atomicAdd(&cnt[rr[k] >> BROWS_LOG], 1);
    __syncthreads();
    for (int i = threadIdx.x; i < nb; i += 256) {
        int c = cnt[i];
        cnt[i] = (c > 0) ? atomicAdd(&bucket_cursor[i], c) : 0;  // global base
    }
    __syncthreads();
#pragma unroll
    for (int k = 0; k < EPT; k++) {
        if (rr[k] >= 0) {
            int b = rr[k] >> BROWS_LOG;
            int pos = atomicAdd(&cnt[b], 1);  // absolute pos within bucket
            bins[(size_t)b * BINCAP + pos] =
                ((unsigned)(rr[k] & (BROWS - 1)) << 17) | (unsigned)cc[k];
        }
    }
}

// One 512-thread block per bucket, all staged in LDS. Emits UNSORTED,
// dummy-padded CSR + row_info + dis + degree-grouped perm. (Sorting is done
// by sort_rows_kernel afterwards -- massively parallel there.)
__global__ __launch_bounds__(512) void build_csr_kernel(const unsigned* __restrict__ bins,
                                                        const int* __restrict__ bucket_cursor,
                                                        int* __restrict__ csr_col,
                                                        uint2* __restrict__ row_info,
                                                        float* __restrict__ dis,
                                                        int* __restrict__ perm, int n) {
    __shared__ int cnt[512];
    __shared__ int sm[512];
    __shared__ int cur[512];
    __shared__ int lcsr[CSRCAP];  // 48 KB; total static LDS = 54 KB
    int b = blockIdx.x;
    int tid = threadIdx.x;
    int m = bucket_cursor[b];
    cnt[tid] = 0;
    __syncthreads();
    const unsigned* bp = bins + (size_t)b * BINCAP;
    for (int i = tid; i < m; i += 512) atomicAdd(&cnt[bp[i] >> 17], 1);
    __syncthreads();
    int c = cnt[tid];
    int padded = (c + 3) & ~3;
    int r = b * BROWS + tid;
    if (r < n) dis[r] = rsqrtf(1.0f + (float)c);
    sm[tid] = padded;
    __syncthreads();
    for (int off = 1; off < 512; off <<= 1) {
        int t = (tid >= off) ? sm[tid - off] : 0;
        __syncthreads();
        sm[tid] += t;
        __syncthreads();
    }
    int off0 = sm[tid] - padded;  // exclusive scan
    cur[tid] = off0;
    if (r < n) row_info[r] = make_uint2((unsigned)(b * CSRCAP + off0), (unsigned)padded);
    __syncthreads();
    for (int i = tid; i < m; i += 512) {
        unsigned u = bp[i];
        int pos = atomicAdd(&cur[u >> 17], 1);
        lcsr[pos] = (int)(u & 0x1FFFFu);
    }
    __syncthreads();
    // dummy-pad own row's tail (pad slots gather zero row n in SpMM)
    if (r < n) {
        for (int j = c; j < padded; j++) lcsr[off0 + j] = n;
    }
    __syncthreads();
    int tot = sm[511];  // total padded slots (multiple of 4)
    int4* cp4 = (int4*)(csr_col + (size_t)b * CSRCAP);
    const int4* l4 = (const int4*)lcsr;
    for (int i = tid; i < (tot >> 2); i += 512) cp4[i] = l4[i];

    // ---- degree-grouped perm: counting sort of bucket rows by padded len ----
    // (rank order within a bin is nondeterministic, but output is per-row
    //  independent of wave assignment -> bit-identical results.)
    __syncthreads();
    if (tid < 64) cnt[tid] = 0;
    __syncthreads();
    int bin = min(padded >> 2, 63);
    if (r < n) atomicAdd(&cnt[bin], 1);
    __syncthreads();
    if (tid < 64) sm[tid] = cnt[tid];
    __syncthreads();
    for (int off = 1; off < 64; off <<= 1) {
        int t = (tid >= off && tid < 64) ? sm[tid - off] : 0;
        __syncthreads();
        if (tid < 64) sm[tid] += t;
        __syncthreads();
    }
    if (tid < 64) cur[tid] = sm[tid] - cnt[tid];  // exclusive bin base
    __syncthreads();
    if (r < n) {
        int rank = atomicAdd(&cur[bin], 1);
        perm[b * BROWS + rank] = r;
    } else {
        perm[b * BROWS + tid] = -1;  // tid >= valid-count exactly when r >= n
    }
}

// Sort each padded CSR row ascending (canonical multiset order -> output is
// bit-identical across replays regardless of scatter order). One half-wave
// (32 lanes) per row via bitonic network; rows with padded>32 (P ~ 1e-3) use
// a 64-lane pass; padded>64 (unreachable for this data) falls back serial.
// Pad entries (value n) sort to the row tail, preserving the pad invariant.
__global__ __launch_bounds__(256) void sort_rows_kernel(int* __restrict__ csr_col,
                                                        const uint2* __restrict__ row_info,
                                                        int n) {
    int wid = (int)((blockIdx.x * blockDim.x + threadIdx.x) >> 6);
    int lane = threadIdx.x & 63;
    int r0 = wid * 2, r1 = r0 + 1;
    if (r0 >= n) return;
    uint2 i0 = row_info[r0];
    uint2 i1 = (r1 < n) ? row_info[r1] : make_uint2(0u, 0u);
    int p0 = (int)i0.y, p1 = (int)i1.y;
    if (p0 <= 32 && p1 <= 32) {
        int half = lane >> 5, hl = lane & 31;
        int base = half ? (int)i1.x : (int)i0.x;
        int pad  = half ? p1 : p0;
        int key = (hl < pad) ? csr_col[base + hl] : 0x7fffffff;
#pragma unroll
        for (int k = 2; k <= 32; k <<= 1) {
#pragma unroll
            for (int j = k >> 1; j > 0; j >>= 1) {
                int other = __shfl_xor(key, j, 64);  // j<32: stays in half
                bool takeMin = (((hl & j) == 0) == ((hl & k) == 0));
                int mn = min(key, other), mx = max(key, other);
                key = takeMin ? mn : mx;
            }
        }
        if (hl < pad) csr_col[base + hl] = key;
    } else {
        for (int t = 0; t < 2; t++) {
            int base = t ? (int)i1.x : (int)i0.x;
            int pad  = t ? p1 : p0;
            if (pad == 0) continue;
            if (pad <= 64) {
                int key = (lane < pad) ? csr_col[base + lane] : 0x7fffffff;
#pragma unroll
                for (int k = 2; k <= 64; k <<= 1) {
#pragma unroll
                    for (int j = k >> 1; j > 0; j >>= 1) {
                        int other = __shfl_xor(key, j, 64);
                        bool takeMin = (((lane & j) == 0) == ((lane & k) == 0));
                        int mn = min(key, other), mx = max(key, other);
                        key = takeMin ? mn : mx;
                    }
                }
                if (lane < pad) csr_col[base + lane] = key;
            } else if (lane == 0) {
                for (int i2 = 1; i2 < pad; i2++) {
                    int kk = csr_col[base + i2];
                    int j2 = i2 - 1;
                    while (j2 >= 0 && csr_col[base + j2] > kk) {
                        csr_col[base + j2 + 1] = csr_col[base + j2]; j2--;
                    }
                    csr_col[base + j2 + 1] = kk;
                }
            }
        }
    }
}

// xs0[i] = bf16(dis[i] * x[i,:]) packed 2/dword; dummy rows (n) of BOTH xs
// arrays zeroed (pad slots gather row n).
__global__ void scale_x_kernel(const float* __restrict__ x, const float* __restrict__ dis,
                               unsigned* __restrict__ xs0, unsigned* __restrict__ xs1, int n) {
    int i = blockIdx.x * blockDim.x + threadIdx.x;  // over (n+1)*32 dwords
    int total = (n + 1) * (D_FEAT / 2);
    if (i >= total) return;
    int node = i >> 5;
    if (node < n) {
        float s = dis[node];
        float2 v = ((const float2*)x)[i];
        xs0[i] = pack_bf16_2(s * v.x, s * v.y);
    } else {
        xs0[i] = 0u;
        xs1[i] = 0u;  // dummy row of hop-1 output
    }
}

// Gather 16 slots (4 predicated groups of 4) for one quarter's row chunk.
// Accumulates into v2f h01 (features 4ql,4ql+1) and h23 (4ql+2,4ql+3).
#define GATHER16(cp, xs_in, ql, base, len)                                  \
    uint2 u0 = make_uint2(0u, 0u), u1 = u0, u2 = u0, u3 = u0;               \
    uint2 u4 = u0, u5 = u0, u6 = u0, u7 = u0;                               \
    uint2 u8 = u0, u9 = u0, u10 = u0, u11 = u0;                             \
    uint2 u12 = u0, u13 = u0, u14 = u0, u15 = u0;                           \
    if (base < len) {                                                       \
        uint4 cv = cp[(base >> 2) + 0];                                     \
        u0 = xs_in[cv.x * 16 + ql]; u1 = xs_in[cv.y * 16 + ql];             \
        u2 = xs_in[cv.z * 16 + ql]; u3 = xs_in[cv.w * 16 + ql];             \
    }                                                                       \
    if (base + 4 < len) {                                                   \
        uint4 cv = cp[(base >> 2) + 1];                                     \
        u4 = xs_in[cv.x * 16 + ql]; u5 = xs_in[cv.y * 16 + ql];             \
        u6 = xs_in[cv.z * 16 + ql]; u7 = xs_in[cv.w * 16 + ql];             \
    }                                                                       \
    if (base + 8 < len) {                                                   \
        uint4 cv = cp[(base >> 2) + 2];                                     \
        u8 = xs_in[cv.x * 16 + ql]; u9 = xs_in[cv.y * 16 + ql];             \
        u10 = xs_in[cv.z * 16 + ql]; u11 = xs_in[cv.w * 16 + ql];           \
    }                                                                       \
    if (base + 12 < len) {                                                  \
        uint4 cv = cp[(base >> 2) + 3];                                     \
        u12 = xs_in[cv.x * 16 + ql]; u13 = xs_in[cv.y * 16 + ql];           \
        u14 = xs_in[cv.z * 16 + ql]; u15 = xs_in[cv.w * 16 + ql];           \
    }                                                                       \
    acc2p(u0.x, h01); acc2p(u0.y, h23);                                     \
    acc2p(u1.x, h01); acc2p(u1.y, h23);                                     \
    acc2p(u2.x, h01); acc2p(u2.y, h23);                                     \
    acc2p(u3.x, h01); acc2p(u3.y, h23);                                     \
    acc2p(u4.x, h01); acc2p(u4.y, h23);                                     \
    acc2p(u5.x, h01); acc2p(u5.y, h23);                                     \
    acc2p(u6.x, h01); acc2p(u6.y, h23);                                     \
    acc2p(u7.x, h01); acc2p(u7.y, h23);                                     \
    acc2p(u8.x, h01); acc2p(u8.y, h23);                                     \
    acc2p(u9.x, h01); acc2p(u9.y, h23);                                     \
    acc2p(u10.x, h01); acc2p(u10.y, h23);                                   \
    acc2p(u11.x, h01); acc2p(u11.y, h23);                                   \
    acc2p(u12.x, h01); acc2p(u12.y, h23);                                   \
    acc2p(u13.x, h01); acc2p(u13.y, h23);                                   \
    acc2p(u14.x, h01); acc2p(u14.y, h23);                                   \
    acc2p(u15.x, h01); acc2p(u15.y, h23);

// Hop 1: xs1[r,:] = bf16( dis[r]^2 * ( xs0[r,:] + sum_c xs0[c,:] ) ).
// Wave w processes rows perm[4w+q]; lane (q,ql) holds features 4ql..4ql+3.
__global__ __launch_bounds__(256, 6) void spmm_hop1_kernel(const uint2* __restrict__ xs_in,
                                                           uint2* __restrict__ xs_out,
                                                           const int* __restrict__ perm,
                                                           const uint2* __restrict__ row_info,
                                                           const int* __restrict__ csr_col,
                                                           const float* __restrict__ dis,
                                                           int n, int nperm) {
    int wave = (blockIdx.x * blockDim.x + threadIdx.x) >> 6;
    int lane = threadIdx.x & 63;
    int q = lane >> 4, ql = lane & 15;
    int pidx = wave * 4 + q;
    int r = (pidx < nperm) ? perm[pidx] : -1;
    bool valid = (r >= 0);
    int s = 0, len = 0;
    if (valid) { uint2 info = row_info[r]; s = (int)info.x; len = (int)info.y; }
    int maxlen = len;
    maxlen = max(maxlen, __shfl_xor(maxlen, 16, 64));
    maxlen = max(maxlen, __shfl_xor(maxlen, 32, 64));

    v2f h01 = {0.f, 0.f}, h23 = {0.f, 0.f};
    const uint4* cp = (const uint4*)(csr_col + s);  // s is a multiple of 4
    for (int base = 0; base < maxlen; base += 16) {
        GATHER16(cp, xs_in, ql, base, len)
    }
    if (valid) {
        uint2 us = xs_in[r * 16 + ql];  // self term
        acc2p(us.x, h01); acc2p(us.y, h23);
        float dr = dis[r];
        float dr2 = dr * dr;
        xs_out[r * 16 + ql] = make_uint2(pack_bf16_2(dr2 * h01.x, dr2 * h01.y),
                                         pack_bf16_2(dr2 * h23.x, dr2 * h23.y));
    }
}

// Hop 2 fused with logits + log_softmax. h2[r,:] = dis[r]*(xs1[r,:]+sum_c xs1[c,:]).
// GEMV: per-wave LDS transpose of h (hl, padded) + transposed padded Wt;
// lane ql covers classes ql, ql+16, (ql<8) ql+32. Inner loop is broadcast
// ds_read_b128 + FMA only (no shfl, no scalar W reads).
__global__ __launch_bounds__(256, 6) void spmm_logits_kernel(const uint2* __restrict__ xs_in,
                                                             const int* __restrict__ perm,
                                                             const uint2* __restrict__ row_info,
                                                             const int* __restrict__ csr_col,
                                                             const float* __restrict__ dis,
                                                             const float* __restrict__ W,
                                                             const float* __restrict__ b,
                                                             float* __restrict__ out,
                                                             int n, int nperm) {
    __shared__ float Wt[NCLS][D_FEAT + 4];  // transposed, padded: 2-lane/bank max
    __shared__ float bl[NCLS];
    __shared__ float hl[16][D_FEAT + 4];    // 4 waves x 4 rows; padded rows
    for (int i = threadIdx.x; i < D_FEAT * NCLS; i += 256) {
        int d = i / NCLS, cc = i - d * NCLS;
        Wt[cc][d] = W[i];
    }
    for (int i = threadIdx.x; i < NCLS; i += 256) bl[i] = b[i];
    __syncthreads();

    int wave = (blockIdx.x * blockDim.x + threadIdx.x) >> 6;
    int lane = threadIdx.x & 63;
    int q = lane >> 4, ql = lane & 15;
    int pidx = wave * 4 + q;
    int r = (pidx < nperm) ? perm[pidx] : -1;
    bool valid = (r >= 0);
    int s = 0, len = 0;
    if (valid) { uint2 info = row_info[r]; s = (int)info.x; len = (int)info.y; }
    int maxlen = len;
    maxlen = max(maxlen, __shfl_xor(maxlen, 16, 64));
    maxlen = max(maxlen, __shfl_xor(maxlen, 32, 64));

    v2f h01 = {0.f, 0.f}, h23 = {0.f, 0.f};
    const uint4* cp = (const uint4*)(csr_col + s);
    for (int base = 0; base < maxlen; base += 16) {
        GATHER16(cp, xs_in, ql, base, len)
    }

    float y0, y1, y2;
    int c0 = ql, c1 = ql + 16;
    int c2 = (ql < 8) ? (ql + 32) : ql;  // dup addr -> broadcast, no conflict
    {
        uint2 us = valid ? xs_in[r * 16 + ql] : make_uint2(0u, 0u);  // self term
        acc2p(us.x, h01); acc2p(us.y, h23);
        float dr = valid ? dis[r] : 0.f;
        float h0 = h01.x * dr, h1 = h01.y * dr, h2 = h23.x * dr, h3 = h23.y * dr;

        // per-wave transpose: row's 64 features laid out in hl[rowslot][*].
        // Same-wave produce->consume via LDS (lockstep; compiler inserts
        // lgkmcnt ordering for may-alias LDS ops) -- no barrier needed.
        int rowslot = ((threadIdx.x >> 6) << 2) + q;
        *(float4*)&hl[rowslot][ql * 4] = make_float4(h0, h1, h2, h3);

        y0 = bl[c0]; y1 = bl[c1]; y2 = bl[c2];
#pragma unroll
        for (int g = 0; g < 16; g++) {
            float4 hv = *(const float4*)&hl[rowslot][g * 4];   // quarter-broadcast
            float4 w0 = *(const float4*)&Wt[c0][g * 4];
            float4 w1 = *(const float4*)&Wt[c1][g * 4];
            float4 w2 = *(const float4*)&Wt[c2][g * 4];
            y0 += hv.x * w0.x + hv.y * w0.y + hv.z * w0.z + hv.w * w0.w;
            y1 += hv.x * w1.x + hv.y * w1.y + hv.z * w1.z + hv.w * w1.w;
            y2 += hv.x * w2.x + hv.y * w2.y + hv.z * w2.z + hv.w * w2.w;
        }
    }

    bool has3 = (ql < 8);
    float m = fmaxf(y0, y1);
    if (has3) m = fmaxf(m, y2);
#pragma unroll
    for (int o = 8; o > 0; o >>= 1) m = fmaxf(m, __shfl_xor(m, o, 64));
    float sm = __expf(y0 - m) + __expf(y1 - m) + (has3 ? __expf(y2 - m) : 0.f);
#pragma unroll
    for (int o = 8; o > 0; o >>= 1) sm += __shfl_xor(sm, o, 64);
    float lse = m + __logf(sm);

    if (valid) {
        float* op = out + (long long)r * NCLS;
        op[ql] = y0 - lse;
        op[ql + 16] = y1 - lse;
        if (has3) op[ql + 32] = y2 - lse;
    }
}

extern "C" void kernel_launch(void* const* d_in, const int* in_sizes, int n_in,
                              void* d_out, int out_size, void* d_ws, size_t ws_size,
                              hipStream_t stream) {
    const float* x  = (const float*)d_in[0];
    const int*   ei = (const int*)d_in[1];   // [2, E] flat: rows then cols (int32)
    const float* W  = (const float*)d_in[2]; // [64, 40]
    const float* b  = (const float*)d_in[3]; // [40]
    float* out = (float*)d_out;

    const int n = in_sizes[0] / D_FEAT;      // 100000
    const int e = in_sizes[1] / 2;           // 1600000
    const int nb = (n + BROWS - 1) / BROWS;  // 196

    const int* rows = ei;
    const int* cols = ei + e;

    // ws layout (int units, segments aligned):
    //   bucket_cursor[nb] | dis[n] | row_info[n] (uint2) | perm[nb*512] |
    //   bins[nb*BINCAP] | csr_col[nb*CSRCAP] | xs0 | xs1       (~45 MB)
    size_t na = ((size_t)n + 256) & ~(size_t)255;
    size_t npm = (size_t)nb * BROWS;         // multiple of 512
    int*      bucket_cursor = (int*)d_ws;
    float*    dis           = (float*)(bucket_cursor + 256);
    uint2*    row_info      = (uint2*)(dis + na);
    int*      perm          = (int*)(row_info + na);
    unsigned* bins          = (unsigned*)(perm + npm);
    int*      csr_col       = (int*)(bins + (size_t)nb * BINCAP);
    unsigned* xs0           = (unsigned*)(csr_col + (size_t)nb * CSRCAP);
    unsigned* xs1           = xs0 + (size_t)(n + 1) * (D_FEAT / 2);

    const int BS = 256;

    zero_cursors_kernel<<<1, 256, 0, stream>>>(bucket_cursor, nb);
    {
        int blocks = (e + BS * EPT - 1) / (BS * EPT);  // 250
        bin_edges_kernel<<<blocks, BS, 0, stream>>>(rows, cols, bucket_cursor, bins, e, nb);
    }
    build_csr_kernel<<<nb, 512, 0, stream>>>(bins, bucket_cursor, csr_col, row_info, dis,
                                             perm, n);
    {
        // one half-wave per row, 2 rows per wave, 4 waves per block
        int nwv = (n + 1) / 2;
        int blocks = (nwv * 64 + BS - 1) / BS;
        sort_rows_kernel<<<blocks, BS, 0, stream>>>(csr_col, row_info, n);
    }
    {
        int tot = (n + 1) * (D_FEAT / 2);
        scale_x_kernel<<<(tot + BS - 1) / BS, BS, 0, stream>>>(x, dis, xs0, xs1, n);
    }

    int nperm = (int)npm;                    // nb*512 perm slots
    int nwaves = nperm / 4;                  // 4 rows per wave
    int blocks = (nwaves * 64 + BS - 1) / BS;
    spmm_hop1_kernel<<<blocks, BS, 0, stream>>>((const uint2*)xs0, (uint2*)xs1, perm,
                                                row_info, csr_col, dis, n, nperm);
    spmm_logits_kernel<<<blocks, BS, 0, stream>>>((const uint2*)xs1, perm, row_info, csr_col,
                                                  dis, W, b, out, n, nperm);
}

// Round 4
// 210.985 us; speedup vs baseline: 1.1872x; 1.0037x over previous
//
#include <hip/hip_runtime.h>
#include <math.h>

// SGC: K=2 hops of D^-1/2 (A+I) D^-1/2, then x@W+b, then log_softmax.
// N=100000, D=64, C=40, E=1600000.
//
// R12 (this round): cut zero-work in the gather loop.
//  - accumulates now predicated per 4-slot group (same conds as loads, in
//    SEPARATE if-blocks after all loads -> MLP preserved, dead groups skip
//    their VALU via execz). Mean real slots 17.5 vs 32 executed before.
//  - u0..u15 zero-init deleted (only read under the condition that wrote them).
//  - dual accumulator pairs (groups 0,2 -> hA; 1,3 -> hB) halve the
//    v_pk_add_f32 dependency chain; merged once after the loop.
//  - zero_cursors kernel replaced by hipMemsetAsync.
//
// Carried: sort_rows bitonic kernel (R11), degree-grouped perm, pk_add
// accumulate, LDS-transpose GEMV epilogue, launch_bounds(256,6) on SpMM.

#define D_FEAT 64
#define NCLS 40
#define BROWS 512       // rows per bucket
#define BROWS_LOG 9
#define BINCAP 10240    // per-bucket edge capacity (mean 8192, sd ~90)
#define CSRCAP 12288    // per-bucket csr capacity (max padded = 10240+3*512 = 11776)
#define EPT 25          // edges per thread in bin_edges (250 blocks)

typedef float v2f __attribute__((ext_vector_type(2)));

__device__ __forceinline__ unsigned pack_bf16_2(float lo, float hi) {
    unsigned ulo = __float_as_uint(lo);
    unsigned uhi = __float_as_uint(hi);
    ulo = (ulo + 0x7fffu + ((ulo >> 16) & 1u)) >> 16;           // RNE
    uhi = (uhi + 0x7fffu + ((uhi >> 16) & 1u)) & 0xffff0000u;   // RNE
    return uhi | ulo;
}

// packed-accumulate one dword (2 bf16 features) into a float2 accumulator
__device__ __forceinline__ void acc2p(unsigned u, v2f& a) {
    v2f v;
    v.x = __uint_as_float(u << 16);
    v.y = __uint_as_float(u & 0xffff0000u);
    a += v;   // <2 x float> fadd -> v_pk_add_f32
}

// Bin edges into per-bucket regions. Packed entry: (row&511)<<17 | col.
// (Requires n <= 131072 so col fits 17 bits; n = 100000 here.)
__global__ __launch_bounds__(256) void bin_edges_kernel(const int* __restrict__ rows,
                                                        const int* __restrict__ cols,
                                                        int* __restrict__ bucket_cursor,
                                                        unsigned* __restrict__ bins,
                                                        int e, int nb) {
    __shared__ int cnt[512];
    for (int i = threadIdx.x; i < nb; i += 256) cnt[i] = 0;
    __syncthreads();
    int base = blockIdx.x * (256 * EPT) + threadIdx.x;
    int rr[EPT], cc[EPT];
#pragma unroll
    for (int k = 0; k < EPT; k++) {
        int idx = base + k * 256;
        if (idx < e) { rr[k] = rows[idx]; cc[k] = cols[idx]; }
        else { rr[k] = -1; cc[k] = 0; }
    }
#pragma unroll
    for (int k = 0; k < EPT; k++)
        if (rr[k] >= 0) atomicAdd(&cnt[rr[k] >> BROWS_LOG], 1);
    __syncthreads();
    for (int i = threadIdx.x; i < nb; i += 256) {
        int c = cnt[i];
        cnt[i] = (c > 0) ? atomicAdd(&bucket_cursor[i], c) : 0;  // global base
    }
    __syncthreads();
#pragma unroll
    for (int k = 0; k < EPT; k++) {
        if (rr[k] >= 0) {
            int b = rr[k] >> BROWS_LOG;
            int pos = atomicAdd(&cnt[b], 1);  // absolute pos within bucket
            bins[(size_t)b * BINCAP + pos] =
                ((unsigned)(rr[k] & (BROWS - 1)) << 17) | (unsigned)cc[k];
        }
    }
}

// One 512-thread block per bucket, all staged in LDS. Emits UNSORTED,
// dummy-padded CSR + row_info + dis + degree-grouped perm. (Sorting is done
// by sort_rows_kernel afterwards -- massively parallel there.)
__global__ __launch_bounds__(512) void build_csr_kernel(const unsigned* __restrict__ bins,
                                                        const int* __restrict__ bucket_cursor,
                                                        int* __restrict__ csr_col,
                                                        uint2* __restrict__ row_info,
                                                        float* __restrict__ dis,
                                                        int* __restrict__ perm, int n) {
    __shared__ int cnt[512];
    __shared__ int sm[512];
    __shared__ int cur[512];
    __shared__ int lcsr[CSRCAP];  // 48 KB; total static LDS = 54 KB
    int b = blockIdx.x;
    int tid = threadIdx.x;
    int m = bucket_cursor[b];
    cnt[tid] = 0;
    __syncthreads();
    const unsigned* bp = bins + (size_t)b * BINCAP;
    for (int i = tid; i < m; i += 512) atomicAdd(&cnt[bp[i] >> 17], 1);
    __syncthreads();
    int c = cnt[tid];
    int padded = (c + 3) & ~3;
    int r = b * BROWS + tid;
    if (r < n) dis[r] = rsqrtf(1.0f + (float)c);
    sm[tid] = padded;
    __syncthreads();
    for (int off = 1; off < 512; off <<= 1) {
        int t = (tid >= off) ? sm[tid - off] : 0;
        __syncthreads();
        sm[tid] += t;
        __syncthreads();
    }
    int off0 = sm[tid] - padded;  // exclusive scan
    cur[tid] = off0;
    if (r < n) row_info[r] = make_uint2((unsigned)(b * CSRCAP + off0), (unsigned)padded);
    __syncthreads();
    for (int i = tid; i < m; i += 512) {
        unsigned u = bp[i];
        int pos = atomicAdd(&cur[u >> 17], 1);
        lcsr[pos] = (int)(u & 0x1FFFFu);
    }
    __syncthreads();
    // dummy-pad own row's tail (pad slots gather zero row n in SpMM)
    if (r < n) {
        for (int j = c; j < padded; j++) lcsr[off0 + j] = n;
    }
    __syncthreads();
    int tot = sm[511];  // total padded slots (multiple of 4)
    int4* cp4 = (int4*)(csr_col + (size_t)b * CSRCAP);
    const int4* l4 = (const int4*)lcsr;
    for (int i = tid; i < (tot >> 2); i += 512) cp4[i] = l4[i];

    // ---- degree-grouped perm: counting sort of bucket rows by padded len ----
    // (rank order within a bin is nondeterministic, but output is per-row
    //  independent of wave assignment -> bit-identical results.)
    __syncthreads();
    if (tid < 64) cnt[tid] = 0;
    __syncthreads();
    int bin = min(padded >> 2, 63);
    if (r < n) atomicAdd(&cnt[bin], 1);
    __syncthreads();
    if (tid < 64) sm[tid] = cnt[tid];
    __syncthreads();
    for (int off = 1; off < 64; off <<= 1) {
        int t = (tid >= off && tid < 64) ? sm[tid - off] : 0;
        __syncthreads();
        if (tid < 64) sm[tid] += t;
        __syncthreads();
    }
    if (tid < 64) cur[tid] = sm[tid] - cnt[tid];  // exclusive bin base
    __syncthreads();
    if (r < n) {
        int rank = atomicAdd(&cur[bin], 1);
        perm[b * BROWS + rank] = r;
    } else {
        perm[b * BROWS + tid] = -1;  // tid >= valid-count exactly when r >= n
    }
}

// Sort each padded CSR row ascending (canonical multiset order -> output is
// bit-identical across replays regardless of scatter order). One half-wave
// (32 lanes) per row via bitonic network; rows with padded>32 (P ~ 1e-3) use
// a 64-lane pass; padded>64 (unreachable for this data) falls back serial.
// Pad entries (value n) sort to the row tail, preserving the pad invariant.
__global__ __launch_bounds__(256) void sort_rows_kernel(int* __restrict__ csr_col,
                                                        const uint2* __restrict__ row_info,
                                                        int n) {
    int wid = (int)((blockIdx.x * blockDim.x + threadIdx.x) >> 6);
    int lane = threadIdx.x & 63;
    int r0 = wid * 2, r1 = r0 + 1;
    if (r0 >= n) return;
    uint2 i0 = row_info[r0];
    uint2 i1 = (r1 < n) ? row_info[r1] : make_uint2(0u, 0u);
    int p0 = (int)i0.y, p1 = (int)i1.y;
    if (p0 <= 32 && p1 <= 32) {
        int half = lane >> 5, hl = lane & 31;
        int base = half ? (int)i1.x : (int)i0.x;
        int pad  = half ? p1 : p0;
        int key = (hl < pad) ? csr_col[base + hl] : 0x7fffffff;
#pragma unroll
        for (int k = 2; k <= 32; k <<= 1) {
#pragma unroll
            for (int j = k >> 1; j > 0; j >>= 1) {
                int other = __shfl_xor(key, j, 64);  // j<32: stays in half
                bool takeMin = (((hl & j) == 0) == ((hl & k) == 0));
                int mn = min(key, other), mx = max(key, other);
                key = takeMin ? mn : mx;
            }
        }
        if (hl < pad) csr_col[base + hl] = key;
    } else {
        for (int t = 0; t < 2; t++) {
            int base = t ? (int)i1.x : (int)i0.x;
            int pad  = t ? p1 : p0;
            if (pad == 0) continue;
            if (pad <= 64) {
                int key = (lane < pad) ? csr_col[base + lane] : 0x7fffffff;
#pragma unroll
                for (int k = 2; k <= 64; k <<= 1) {
#pragma unroll
                    for (int j = k >> 1; j > 0; j >>= 1) {
                        int other = __shfl_xor(key, j, 64);
                        bool takeMin = (((lane & j) == 0) == ((lane & k) == 0));
                        int mn = min(key, other), mx = max(key, other);
                        key = takeMin ? mn : mx;
                    }
                }
                if (lane < pad) csr_col[base + lane] = key;
            } else if (lane == 0) {
                for (int i2 = 1; i2 < pad; i2++) {
                    int kk = csr_col[base + i2];
                    int j2 = i2 - 1;
                    while (j2 >= 0 && csr_col[base + j2] > kk) {
                        csr_col[base + j2 + 1] = csr_col[base + j2]; j2--;
                    }
                    csr_col[base + j2 + 1] = kk;
                }
            }
        }
    }
}

// xs0[i] = bf16(dis[i] * x[i,:]) packed 2/dword; dummy rows (n) of BOTH xs
// arrays zeroed (pad slots gather row n).
__global__ void scale_x_kernel(const float* __restrict__ x, const float* __restrict__ dis,
                               unsigned* __restrict__ xs0, unsigned* __restrict__ xs1, int n) {
    int i = blockIdx.x * blockDim.x + threadIdx.x;  // over (n+1)*32 dwords
    int total = (n + 1) * (D_FEAT / 2);
    if (i >= total) return;
    int node = i >> 5;
    if (node < n) {
        float s = dis[node];
        float2 v = ((const float2*)x)[i];
        xs0[i] = pack_bf16_2(s * v.x, s * v.y);
    } else {
        xs0[i] = 0u;
        xs1[i] = 0u;  // dummy row of hop-1 output
    }
}

// Gather 16 slots (4 predicated groups of 4) for one quarter's row chunk.
// Loads all issue first (MLP); accumulates are predicated by the SAME group
// conditions in separate if-blocks -> dead groups skip their VALU entirely.
// u's are uninitialized but only read under the condition that wrote them.
// Groups 0,2 feed hA*, groups 1,3 feed hB* (halved dependency chain).
#define GATHER16(cp, xs_in, ql, base, len)                                  \
    uint2 u0, u1, u2, u3, u4, u5, u6, u7;                                   \
    uint2 u8, u9, u10, u11, u12, u13, u14, u15;                             \
    bool g0 = base < len, g1 = base + 4 < len;                              \
    bool g2 = base + 8 < len, g3 = base + 12 < len;                         \
    if (g0) {                                                               \
        uint4 cv = cp[(base >> 2) + 0];                                     \
        u0 = xs_in[cv.x * 16 + ql]; u1 = xs_in[cv.y * 16 + ql];             \
        u2 = xs_in[cv.z * 16 + ql]; u3 = xs_in[cv.w * 16 + ql];             \
    }                                                                       \
    if (g1) {                                                               \
        uint4 cv = cp[(base >> 2) + 1];                                     \
        u4 = xs_in[cv.x * 16 + ql]; u5 = xs_in[cv.y * 16 + ql];             \
        u6 = xs_in[cv.z * 16 + ql]; u7 = xs_in[cv.w * 16 + ql];             \
    }                                                                       \
    if (g2) {                                                               \
        uint4 cv = cp[(base >> 2) + 2];                                     \
        u8 = xs_in[cv.x * 16 + ql]; u9 = xs_in[cv.y * 16 + ql];             \
        u10 = xs_in[cv.z * 16 + ql]; u11 = xs_in[cv.w * 16 + ql];           \
    }                                                                       \
    if (g3) {                                                               \
        uint4 cv = cp[(base >> 2) + 3];                                     \
        u12 = xs_in[cv.x * 16 + ql]; u13 = xs_in[cv.y * 16 + ql];           \
        u14 = xs_in[cv.z * 16 + ql]; u15 = xs_in[cv.w * 16 + ql];           \
    }                                                                       \
    if (g0) {                                                               \
        acc2p(u0.x, hA01); acc2p(u0.y, hA23);                               \
        acc2p(u1.x, hA01); acc2p(u1.y, hA23);                               \
        acc2p(u2.x, hA01); acc2p(u2.y, hA23);                               \
        acc2p(u3.x, hA01); acc2p(u3.y, hA23);                               \
    }                                                                       \
    if (g1) {                                                               \
        acc2p(u4.x, hB01); acc2p(u4.y, hB23);                               \
        acc2p(u5.x, hB01); acc2p(u5.y, hB23);                               \
        acc2p(u6.x, hB01); acc2p(u6.y, hB23);                               \
        acc2p(u7.x, hB01); acc2p(u7.y, hB23);                               \
    }                                                                       \
    if (g2) {                                                               \
        acc2p(u8.x, hA01); acc2p(u8.y, hA23);                               \
        acc2p(u9.x, hA01); acc2p(u9.y, hA23);                               \
        acc2p(u10.x, hA01); acc2p(u10.y, hA23);                             \
        acc2p(u11.x, hA01); acc2p(u11.y, hA23);                             \
    }                                                                       \
    if (g3) {                                                               \
        acc2p(u12.x, hB01); acc2p(u12.y, hB23);                             \
        acc2p(u13.x, hB01); acc2p(u13.y, hB23);                             \
        acc2p(u14.x, hB01); acc2p(u14.y, hB23);                             \
        acc2p(u15.x, hB01); acc2p(u15.y, hB23);                             \
    }

// Hop 1: xs1[r,:] = bf16( dis[r]^2 * ( xs0[r,:] + sum_c xs0[c,:] ) ).
// Wave w processes rows perm[4w+q]; lane (q,ql) holds features 4ql..4ql+3.
__global__ __launch_bounds__(256, 6) void spmm_hop1_kernel(const uint2* __restrict__ xs_in,
                                                           uint2* __restrict__ xs_out,
                                                           const int* __restrict__ perm,
                                                           const uint2* __restrict__ row_info,
                                                           const int* __restrict__ csr_col,
                                                           const float* __restrict__ dis,
                                                           int n, int nperm) {
    int wave = (blockIdx.x * blockDim.x + threadIdx.x) >> 6;
    int lane = threadIdx.x & 63;
    int q = lane >> 4, ql = lane & 15;
    int pidx = wave * 4 + q;
    int r = (pidx < nperm) ? perm[pidx] : -1;
    bool valid = (r >= 0);
    int s = 0, len = 0;
    if (valid) { uint2 info = row_info[r]; s = (int)info.x; len = (int)info.y; }
    int maxlen = len;
    maxlen = max(maxlen, __shfl_xor(maxlen, 16, 64));
    maxlen = max(maxlen, __shfl_xor(maxlen, 32, 64));

    v2f hA01 = {0.f, 0.f}, hA23 = {0.f, 0.f};
    v2f hB01 = {0.f, 0.f}, hB23 = {0.f, 0.f};
    const uint4* cp = (const uint4*)(csr_col + s);  // s is a multiple of 4
    for (int base = 0; base < maxlen; base += 16) {
        GATHER16(cp, xs_in, ql, base, len)
    }
    if (valid) {
        v2f h01 = hA01 + hB01;
        v2f h23 = hA23 + hB23;
        uint2 us = xs_in[r * 16 + ql];  // self term
        acc2p(us.x, h01); acc2p(us.y, h23);
        float dr = dis[r];
        float dr2 = dr * dr;
        xs_out[r * 16 + ql] = make_uint2(pack_bf16_2(dr2 * h01.x, dr2 * h01.y),
                                         pack_bf16_2(dr2 * h23.x, dr2 * h23.y));
    }
}

// Hop 2 fused with logits + log_softmax. h2[r,:] = dis[r]*(xs1[r,:]+sum_c xs1[c,:]).
// GEMV: per-wave LDS transpose of h (hl, padded) + transposed padded Wt;
// lane ql covers classes ql, ql+16, (ql<8) ql+32. Inner loop is broadcast
// ds_read_b128 + FMA only (no shfl, no scalar W reads).
__global__ __launch_bounds__(256, 6) void spmm_logits_kernel(const uint2* __restrict__ xs_in,
                                                             const int* __restrict__ perm,
                                                             const uint2* __restrict__ row_info,
                                                             const int* __restrict__ csr_col,
                                                             const float* __restrict__ dis,
                                                             const float* __restrict__ W,
                                                             const float* __restrict__ b,
                                                             float* __restrict__ out,
                                                             int n, int nperm) {
    __shared__ float Wt[NCLS][D_FEAT + 4];  // transposed, padded: 2-lane/bank max
    __shared__ float bl[NCLS];
    __shared__ float hl[16][D_FEAT + 4];    // 4 waves x 4 rows; padded rows
    for (int i = threadIdx.x; i < D_FEAT * NCLS; i += 256) {
        int d = i / NCLS, cc = i - d * NCLS;
        Wt[cc][d] = W[i];
    }
    for (int i = threadIdx.x; i < NCLS; i += 256) bl[i] = b[i];
    __syncthreads();

    int wave = (blockIdx.x * blockDim.x + threadIdx.x) >> 6;
    int lane = threadIdx.x & 63;
    int q = lane >> 4, ql = lane & 15;
    int pidx = wave * 4 + q;
    int r = (pidx < nperm) ? perm[pidx] : -1;
    bool valid = (r >= 0);
    int s = 0, len = 0;
    if (valid) { uint2 info = row_info[r]; s = (int)info.x; len = (int)info.y; }
    int maxlen = len;
    maxlen = max(maxlen, __shfl_xor(maxlen, 16, 64));
    maxlen = max(maxlen, __shfl_xor(maxlen, 32, 64));

    v2f hA01 = {0.f, 0.f}, hA23 = {0.f, 0.f};
    v2f hB01 = {0.f, 0.f}, hB23 = {0.f, 0.f};
    const uint4* cp = (const uint4*)(csr_col + s);
    for (int base = 0; base < maxlen; base += 16) {
        GATHER16(cp, xs_in, ql, base, len)
    }

    float y0, y1, y2;
    int c0 = ql, c1 = ql + 16;
    int c2 = (ql < 8) ? (ql + 32) : ql;  // dup addr -> broadcast, no conflict
    {
        v2f h01 = hA01 + hB01;
        v2f h23 = hA23 + hB23;
        uint2 us = valid ? xs_in[r * 16 + ql] : make_uint2(0u, 0u);  // self term
        acc2p(us.x, h01); acc2p(us.y, h23);
        float dr = valid ? dis[r] : 0.f;
        float h0 = h01.x * dr, h1 = h01.y * dr, h2 = h23.x * dr, h3 = h23.y * dr;

        // per-wave transpose: row's 64 features laid out in hl[rowslot][*].
        // Same-wave produce->consume via LDS (lockstep; compiler inserts
        // lgkmcnt ordering for may-alias LDS ops) -- no barrier needed.
        int rowslot = ((threadIdx.x >> 6) << 2) + q;
        *(float4*)&hl[rowslot][ql * 4] = make_float4(h0, h1, h2, h3);

        y0 = bl[c0]; y1 = bl[c1]; y2 = bl[c2];
#pragma unroll
        for (int g = 0; g < 16; g++) {
            float4 hv = *(const float4*)&hl[rowslot][g * 4];   // quarter-broadcast
            float4 w0 = *(const float4*)&Wt[c0][g * 4];
            float4 w1 = *(const float4*)&Wt[c1][g * 4];
            float4 w2 = *(const float4*)&Wt[c2][g * 4];
            y0 += hv.x * w0.x + hv.y * w0.y + hv.z * w0.z + hv.w * w0.w;
            y1 += hv.x * w1.x + hv.y * w1.y + hv.z * w1.z + hv.w * w1.w;
            y2 += hv.x * w2.x + hv.y * w2.y + hv.z * w2.z + hv.w * w2.w;
        }
    }

    bool has3 = (ql < 8);
    float m = fmaxf(y0, y1);
    if (has3) m = fmaxf(m, y2);
#pragma unroll
    for (int o = 8; o > 0; o >>= 1) m = fmaxf(m, __shfl_xor(m, o, 64));
    float sm = __expf(y0 - m) + __expf(y1 - m) + (has3 ? __expf(y2 - m) : 0.f);
#pragma unroll
    for (int o = 8; o > 0; o >>= 1) sm += __shfl_xor(sm, o, 64);
    float lse = m + __logf(sm);

    if (valid) {
        float* op = out + (long long)r * NCLS;
        op[ql] = y0 - lse;
        op[ql + 16] = y1 - lse;
        if (has3) op[ql + 32] = y2 - lse;
    }
}

extern "C" void kernel_launch(void* const* d_in, const int* in_sizes, int n_in,
                              void* d_out, int out_size, void* d_ws, size_t ws_size,
                              hipStream_t stream) {
    const float* x  = (const float*)d_in[0];
    const int*   ei = (const int*)d_in[1];   // [2, E] flat: rows then cols (int32)
    const float* W  = (const float*)d_in[2]; // [64, 40]
    const float* b  = (const float*)d_in[3]; // [40]
    float* out = (float*)d_out;

    const int n = in_sizes[0] / D_FEAT;      // 100000
    const int e = in_sizes[1] / 2;           // 1600000
    const int nb = (n + BROWS - 1) / BROWS;  // 196

    const int* rows = ei;
    const int* cols = ei + e;

    // ws layout (int units, segments aligned):
    //   bucket_cursor[nb] | dis[n] | row_info[n] (uint2) | perm[nb*512] |
    //   bins[nb*BINCAP] | csr_col[nb*CSRCAP] | xs0 | xs1       (~45 MB)
    size_t na = ((size_t)n + 256) & ~(size_t)255;
    size_t npm = (size_t)nb * BROWS;         // multiple of 512
    int*      bucket_cursor = (int*)d_ws;
    float*    dis           = (float*)(bucket_cursor + 256);
    uint2*    row_info      = (uint2*)(dis + na);
    int*      perm          = (int*)(row_info + na);
    unsigned* bins          = (unsigned*)(perm + npm);
    int*      csr_col       = (int*)(bins + (size_t)nb * BINCAP);
    unsigned* xs0           = (unsigned*)(csr_col + (size_t)nb * CSRCAP);
    unsigned* xs1           = xs0 + (size_t)(n + 1) * (D_FEAT / 2);

    const int BS = 256;

    hipMemsetAsync(bucket_cursor, 0, (size_t)nb * sizeof(int), stream);
    {
        int blocks = (e + BS * EPT - 1) / (BS * EPT);  // 250
        bin_edges_kernel<<<blocks, BS, 0, stream>>>(rows, cols, bucket_cursor, bins, e, nb);
    }
    build_csr_kernel<<<nb, 512, 0, stream>>>(bins, bucket_cursor, csr_col, row_info, dis,
                                             perm, n);
    {
        // one half-wave per row, 2 rows per wave, 4 waves per block
        int nwv = (n + 1) / 2;
        int blocks = (nwv * 64 + BS - 1) / BS;
        sort_rows_kernel<<<blocks, BS, 0, stream>>>(csr_col, row_info, n);
    }
    {
        int tot = (n + 1) * (D_FEAT / 2);
        scale_x_kernel<<<(tot + BS - 1) / BS, BS, 0, stream>>>(x, dis, xs0, xs1, n);
    }

    int nperm = (int)npm;                    // nb*512 perm slots
    int nwaves = nperm / 4;                  // 4 rows per wave
    int blocks = (nwaves * 64 + BS - 1) / BS;
    spmm_hop1_kernel<<<blocks, BS, 0, stream>>>((const uint2*)xs0, (uint2*)xs1, perm,
                                                row_info, csr_col, dis, n, nperm);
    spmm_logits_kernel<<<blocks, BS, 0, stream>>>((const uint2*)xs1, perm, row_info, csr_col,
                                                  dis, W, b, out, n, nperm);
}

// Round 5
// 207.410 us; speedup vs baseline: 1.2077x; 1.0172x over previous
//
#include <hip/hip_runtime.h>
#include <math.h>

// SGC: K=2 hops of D^-1/2 (A+I) D^-1/2, then x@W+b, then log_softmax.
// N=100000, D=64, C=40, E=1600000.
//
// R13 (this round): attack gather concurrency (VGPR was stuck at 32 -> ~4-deep
// realized pipeline, latency-bound at 25% HBM / 12% L2).
//  - 8 rows per wave, uint4 (16 B) gathers: lane (e=lane>>3, el=lane&7) owns
//    features 8el..8el+7 of row perm[8*wave+e]. One gather instruction moves
//    1024 B; per-edge instruction count halves.
//  - UNCONDITIONAL loads (4 csr + 16 gather) + sched_barrier(0) before the
//    accumulates: forces all 16 uint4 results live -> ~256 B/lane in flight.
//    Safe because each bucket's CSR now has a 512-entry guard of value n
//    (row n of xs is zeros); accumulates stay group-predicated for
//    correctness. launch_bounds(256,4) gives the registers room.
//  - epilogue: hl[32][72] transpose + Wt[40][72]; 5 classes/lane (exact 40);
//    softmax reduce over xor 1/2/4 within the 8-lane group.
//  - sort_rows and scale_x fused into one kernel (blockIdx split).
//
// Carried: bitonic row sort (R11), degree-grouped perm, pk_add accumulate.

#define D_FEAT 64
#define NCLS 40
#define D_PAD 72        // padded feature stride for LDS tiles
#define BROWS 512       // rows per bucket
#define BROWS_LOG 9
#define BINCAP 10240    // per-bucket edge capacity (mean 8192, sd ~90)
#define CSRCAP 12288    // per-bucket csr capacity (max padded 11776 + 512 guard)
#define EPT 25          // edges per thread in bin_edges (250 blocks)

typedef float v2f __attribute__((ext_vector_type(2)));

__device__ __forceinline__ unsigned pack_bf16_2(float lo, float hi) {
    unsigned ulo = __float_as_uint(lo);
    unsigned uhi = __float_as_uint(hi);
    ulo = (ulo + 0x7fffu + ((ulo >> 16) & 1u)) >> 16;           // RNE
    uhi = (uhi + 0x7fffu + ((uhi >> 16) & 1u)) & 0xffff0000u;   // RNE
    return uhi | ulo;
}

// packed-accumulate one dword (2 bf16 features) into a float2 accumulator
__device__ __forceinline__ void acc2p(unsigned u, v2f& a) {
    v2f v;
    v.x = __uint_as_float(u << 16);
    v.y = __uint_as_float(u & 0xffff0000u);
    a += v;   // <2 x float> fadd -> v_pk_add_f32
}

// Bin edges into per-bucket regions. Packed entry: (row&511)<<17 | col.
// (Requires n <= 131072 so col fits 17 bits; n = 100000 here.)
__global__ __launch_bounds__(256) void bin_edges_kernel(const int* __restrict__ rows,
                                                        const int* __restrict__ cols,
                                                        int* __restrict__ bucket_cursor,
                                                        unsigned* __restrict__ bins,
                                                        int e, int nb) {
    __shared__ int cnt[512];
    for (int i = threadIdx.x; i < nb; i += 256) cnt[i] = 0;
    __syncthreads();
    int base = blockIdx.x * (256 * EPT) + threadIdx.x;
    int rr[EPT], cc[EPT];
#pragma unroll
    for (int k = 0; k < EPT; k++) {
        int idx = base + k * 256;
        if (idx < e) { rr[k] = rows[idx]; cc[k] = cols[idx]; }
        else { rr[k] = -1; cc[k] = 0; }
    }
#pragma unroll
    for (int k = 0; k < EPT; k++)
        if (rr[k] >= 0) atomicAdd(&cnt[rr[k] >> BROWS_LOG], 1);
    __syncthreads();
    for (int i = threadIdx.x; i < nb; i += 256) {
        int c = cnt[i];
        cnt[i] = (c > 0) ? atomicAdd(&bucket_cursor[i], c) : 0;  // global base
    }
    __syncthreads();
#pragma unroll
    for (int k = 0; k < EPT; k++) {
        if (rr[k] >= 0) {
            int b = rr[k] >> BROWS_LOG;
            int pos = atomicAdd(&cnt[b], 1);  // absolute pos within bucket
            bins[(size_t)b * BINCAP + pos] =
                ((unsigned)(rr[k] & (BROWS - 1)) << 17) | (unsigned)cc[k];
        }
    }
}

// One 512-thread block per bucket, all staged in LDS. Emits UNSORTED,
// dummy-padded CSR + 512-entry guard (value n) + row_info + dis + perm.
__global__ __launch_bounds__(512) void build_csr_kernel(const unsigned* __restrict__ bins,
                                                        const int* __restrict__ bucket_cursor,
                                                        int* __restrict__ csr_col,
                                                        uint2* __restrict__ row_info,
                                                        float* __restrict__ dis,
                                                        int* __restrict__ perm, int n) {
    __shared__ int cnt[512];
    __shared__ int sm[512];
    __shared__ int cur[512];
    __shared__ int lcsr[CSRCAP];  // 48 KB; total static LDS = 54 KB
    int b = blockIdx.x;
    int tid = threadIdx.x;
    int m = bucket_cursor[b];
    cnt[tid] = 0;
    __syncthreads();
    const unsigned* bp = bins + (size_t)b * BINCAP;
    for (int i = tid; i < m; i += 512) atomicAdd(&cnt[bp[i] >> 17], 1);
    __syncthreads();
    int c = cnt[tid];
    int padded = (c + 3) & ~3;
    int r = b * BROWS + tid;
    if (r < n) dis[r] = rsqrtf(1.0f + (float)c);
    sm[tid] = padded;
    __syncthreads();
    for (int off = 1; off < 512; off <<= 1) {
        int t = (tid >= off) ? sm[tid - off] : 0;
        __syncthreads();
        sm[tid] += t;
        __syncthreads();
    }
    int off0 = sm[tid] - padded;  // exclusive scan
    cur[tid] = off0;
    if (r < n) row_info[r] = make_uint2((unsigned)(b * CSRCAP + off0), (unsigned)padded);
    __syncthreads();
    for (int i = tid; i < m; i += 512) {
        unsigned u = bp[i];
        int pos = atomicAdd(&cur[u >> 17], 1);
        lcsr[pos] = (int)(u & 0x1FFFFu);
    }
    __syncthreads();
    // dummy-pad own row's tail (pad slots gather zero row n in SpMM)
    if (r < n) {
        for (int j = c; j < padded; j++) lcsr[off0 + j] = n;
    }
    __syncthreads();
    int tot = sm[511];  // total padded slots (multiple of 4)
    int4* cp4 = (int4*)(csr_col + (size_t)b * CSRCAP);
    const int4* l4 = (const int4*)lcsr;
    for (int i = tid; i < (tot >> 2); i += 512) cp4[i] = l4[i];
    // guard region: SpMM loads unconditionally up to maxlen past each row's
    // start; fill the bucket tail with n (gathers the zero row). 512 entries
    // always fit: tot <= 11776, CSRCAP = 12288.
    {
        int g = tot + tid;
        if (g < CSRCAP) csr_col[(size_t)b * CSRCAP + g] = n;
    }

    // ---- degree-grouped perm: counting sort of bucket rows by padded len ----
    // (rank order within a bin is nondeterministic, but output is per-row
    //  independent of wave assignment -> bit-identical results.)
    __syncthreads();
    if (tid < 64) cnt[tid] = 0;
    __syncthreads();
    int bin = min(padded >> 2, 63);
    if (r < n) atomicAdd(&cnt[bin], 1);
    __syncthreads();
    if (tid < 64) sm[tid] = cnt[tid];
    __syncthreads();
    for (int off = 1; off < 64; off <<= 1) {
        int t = (tid >= off && tid < 64) ? sm[tid - off] : 0;
        __syncthreads();
        if (tid < 64) sm[tid] += t;
        __syncthreads();
    }
    if (tid < 64) cur[tid] = sm[tid] - cnt[tid];  // exclusive bin base
    __syncthreads();
    if (r < n) {
        int rank = atomicAdd(&cur[bin], 1);
        perm[b * BROWS + rank] = r;
    } else {
        perm[b * BROWS + tid] = -1;  // tid >= valid-count exactly when r >= n
    }
}

// Fused: [0, sortBlocks) = bitonic per-row sort of csr_col (canonical multiset
// order -> bit-identical output); [sortBlocks, ...) = scale_x.
__global__ __launch_bounds__(256) void sort_scale_kernel(int* __restrict__ csr_col,
                                                         const uint2* __restrict__ row_info,
                                                         const float* __restrict__ x,
                                                         const float* __restrict__ dis,
                                                         unsigned* __restrict__ xs0,
                                                         unsigned* __restrict__ xs1,
                                                         int n, int sortBlocks) {
    if ((int)blockIdx.x >= sortBlocks) {
        // ---- scale_x part: xs0[i] = bf16(dis*x), zero dummy row n ----
        int i = ((int)blockIdx.x - sortBlocks) * 256 + threadIdx.x;
        int total = (n + 1) * (D_FEAT / 2);
        if (i >= total) return;
        int node = i >> 5;
        if (node < n) {
            float s = dis[node];
            float2 v = ((const float2*)x)[i];
            xs0[i] = pack_bf16_2(s * v.x, s * v.y);
        } else {
            xs0[i] = 0u;
            xs1[i] = 0u;  // dummy row of hop-1 output
        }
        return;
    }
    // ---- sort part: one half-wave per row ----
    int wid = ((int)blockIdx.x * 256 + (int)threadIdx.x) >> 6;
    int lane = threadIdx.x & 63;
    int r0 = wid * 2, r1 = r0 + 1;
    if (r0 >= n) return;
    uint2 i0 = row_info[r0];
    uint2 i1 = (r1 < n) ? row_info[r1] : make_uint2(0u, 0u);
    int p0 = (int)i0.y, p1 = (int)i1.y;
    if (p0 <= 32 && p1 <= 32) {
        int half = lane >> 5, hl = lane & 31;
        int base = half ? (int)i1.x : (int)i0.x;
        int pad  = half ? p1 : p0;
        int key = (hl < pad) ? csr_col[base + hl] : 0x7fffffff;
#pragma unroll
        for (int k = 2; k <= 32; k <<= 1) {
#pragma unroll
            for (int j = k >> 1; j > 0; j >>= 1) {
                int other = __shfl_xor(key, j, 64);  // j<32: stays in half
                bool takeMin = (((hl & j) == 0) == ((hl & k) == 0));
                int mn = min(key, other), mx = max(key, other);
                key = takeMin ? mn : mx;
            }
        }
        if (hl < pad) csr_col[base + hl] = key;
    } else {
        for (int t = 0; t < 2; t++) {
            int base = t ? (int)i1.x : (int)i0.x;
            int pad  = t ? p1 : p0;
            if (pad == 0) continue;
            if (pad <= 64) {
                int key = (lane < pad) ? csr_col[base + lane] : 0x7fffffff;
#pragma unroll
                for (int k = 2; k <= 64; k <<= 1) {
#pragma unroll
                    for (int j = k >> 1; j > 0; j >>= 1) {
                        int other = __shfl_xor(key, j, 64);
                        bool takeMin = (((lane & j) == 0) == ((lane & k) == 0));
                        int mn = min(key, other), mx = max(key, other);
                        key = takeMin ? mn : mx;
                    }
                }
                if (lane < pad) csr_col[base + lane] = key;
            } else if (lane == 0) {
                for (int i2 = 1; i2 < pad; i2++) {
                    int kk = csr_col[base + i2];
                    int j2 = i2 - 1;
                    while (j2 >= 0 && csr_col[base + j2] > kk) {
                        csr_col[base + j2 + 1] = csr_col[base + j2]; j2--;
                    }
                    csr_col[base + j2 + 1] = kk;
                }
            }
        }
    }
}

#define ACC4A(u) acc2p(u.x, hA01); acc2p(u.y, hA23); acc2p(u.z, hA45); acc2p(u.w, hA67);
#define ACC4B(u) acc2p(u.x, hB01); acc2p(u.y, hB23); acc2p(u.z, hB45); acc2p(u.w, hB67);

// 16 slots of uint4 gather for 8 rows. ALL loads unconditional (guard region
// makes over-read safe: cols are always <= n, row n is zeros), then a full
// scheduling barrier pins them before the predicated accumulates -> 16 loads
// in flight per wave. Groups 0,2 -> A accs; 1,3 -> B (halved dep chain).
#define GATHER16_U4(cp, xs4, el, base, len)                                 \
    uint4 cv0 = cp[(base >> 2) + 0];                                        \
    uint4 cv1 = cp[(base >> 2) + 1];                                        \
    uint4 cv2 = cp[(base >> 2) + 2];                                        \
    uint4 cv3 = cp[(base >> 2) + 3];                                        \
    uint4 u0 = xs4[cv0.x * 8 + el], u1 = xs4[cv0.y * 8 + el];               \
    uint4 u2 = xs4[cv0.z * 8 + el], u3 = xs4[cv0.w * 8 + el];               \
    uint4 u4 = xs4[cv1.x * 8 + el], u5 = xs4[cv1.y * 8 + el];               \
    uint4 u6 = xs4[cv1.z * 8 + el], u7 = xs4[cv1.w * 8 + el];               \
    uint4 u8 = xs4[cv2.x * 8 + el], u9 = xs4[cv2.y * 8 + el];               \
    uint4 u10 = xs4[cv2.z * 8 + el], u11 = xs4[cv2.w * 8 + el];             \
    uint4 u12 = xs4[cv3.x * 8 + el], u13 = xs4[cv3.y * 8 + el];             \
    uint4 u14 = xs4[cv3.z * 8 + el], u15 = xs4[cv3.w * 8 + el];             \
    __builtin_amdgcn_sched_barrier(0);                                      \
    if (base < len)      { ACC4A(u0)  ACC4A(u1)  ACC4A(u2)  ACC4A(u3)  }    \
    if (base + 4 < len)  { ACC4B(u4)  ACC4B(u5)  ACC4B(u6)  ACC4B(u7)  }    \
    if (base + 8 < len)  { ACC4A(u8)  ACC4A(u9)  ACC4A(u10) ACC4A(u11) }    \
    if (base + 12 < len) { ACC4B(u12) ACC4B(u13) ACC4B(u14) ACC4B(u15) }

// Hop 1: xs1[r,:] = bf16( dis[r]^2 * ( xs0[r,:] + sum_c xs0[c,:] ) ).
// Wave w: rows perm[8w..8w+7]; lane (e,el) holds features 8el..8el+7 of row e.
__global__ __launch_bounds__(256, 4) void spmm_hop1_kernel(const uint4* __restrict__ xs_in,
                                                           uint4* __restrict__ xs_out,
                                                           const int* __restrict__ perm,
                                                           const uint2* __restrict__ row_info,
                                                           const int* __restrict__ csr_col,
                                                           const float* __restrict__ dis,
                                                           int n, int nperm) {
    int wave = (blockIdx.x * blockDim.x + threadIdx.x) >> 6;
    int lane = threadIdx.x & 63;
    int e = lane >> 3, el = lane & 7;
    int pidx = wave * 8 + e;
    int r = (pidx < nperm) ? perm[pidx] : -1;
    bool valid = (r >= 0);
    int s = 0, len = 0;
    if (valid) { uint2 info = row_info[r]; s = (int)info.x; len = (int)info.y; }
    int maxlen = len;
    maxlen = max(maxlen, __shfl_xor(maxlen, 8, 64));
    maxlen = max(maxlen, __shfl_xor(maxlen, 16, 64));
    maxlen = max(maxlen, __shfl_xor(maxlen, 32, 64));

    v2f hA01 = {0.f,0.f}, hA23 = {0.f,0.f}, hA45 = {0.f,0.f}, hA67 = {0.f,0.f};
    v2f hB01 = {0.f,0.f}, hB23 = {0.f,0.f}, hB45 = {0.f,0.f}, hB67 = {0.f,0.f};
    const uint4* cp = (const uint4*)(csr_col + s);  // s is a multiple of 4
    for (int base = 0; base < maxlen; base += 16) {
        GATHER16_U4(cp, xs_in, el, base, len)
    }
    if (valid) {
        v2f h01 = hA01 + hB01, h23 = hA23 + hB23;
        v2f h45 = hA45 + hB45, h67 = hA67 + hB67;
        uint4 us = xs_in[r * 8 + el];  // self term
        acc2p(us.x, h01); acc2p(us.y, h23); acc2p(us.z, h45); acc2p(us.w, h67);
        float dr = dis[r];
        float d2 = dr * dr;
        xs_out[r * 8 + el] = make_uint4(pack_bf16_2(d2 * h01.x, d2 * h01.y),
                                        pack_bf16_2(d2 * h23.x, d2 * h23.y),
                                        pack_bf16_2(d2 * h45.x, d2 * h45.y),
                                        pack_bf16_2(d2 * h67.x, d2 * h67.y));
    }
}

// Hop 2 fused with logits + log_softmax. 8 rows/wave; lane (e,el) covers
// classes el, el+8, el+16, el+24, el+32 (exactly 40). GEMV via hl transpose
// (one-time write; reads broadcast/2-way = conflict-free) + Wt[40][72].
__global__ __launch_bounds__(256, 4) void spmm_logits_kernel(const uint4* __restrict__ xs_in,
                                                             const int* __restrict__ perm,
                                                             const uint2* __restrict__ row_info,
                                                             const int* __restrict__ csr_col,
                                                             const float* __restrict__ dis,
                                                             const float* __restrict__ W,
                                                             const float* __restrict__ b,
                                                             float* __restrict__ out,
                                                             int n, int nperm) {
    __shared__ float Wt[NCLS][D_PAD];
    __shared__ float bl[NCLS];
    __shared__ float hl[32][D_PAD];  // 4 waves x 8 rows
    for (int i = threadIdx.x; i < D_FEAT * NCLS; i += 256) {
        int d = i / NCLS, cc = i - d * NCLS;
        Wt[cc][d] = W[i];
    }
    for (int i = threadIdx.x; i < NCLS; i += 256) bl[i] = b[i];
    __syncthreads();

    int wave = (blockIdx.x * blockDim.x + threadIdx.x) >> 6;
    int lane = threadIdx.x & 63;
    int e = lane >> 3, el = lane & 7;
    int pidx = wave * 8 + e;
    int r = (pidx < nperm) ? perm[pidx] : -1;
    bool valid = (r >= 0);
    int s = 0, len = 0;
    if (valid) { uint2 info = row_info[r]; s = (int)info.x; len = (int)info.y; }
    int maxlen = len;
    maxlen = max(maxlen, __shfl_xor(maxlen, 8, 64));
    maxlen = max(maxlen, __shfl_xor(maxlen, 16, 64));
    maxlen = max(maxlen, __shfl_xor(maxlen, 32, 64));

    v2f hA01 = {0.f,0.f}, hA23 = {0.f,0.f}, hA45 = {0.f,0.f}, hA67 = {0.f,0.f};
    v2f hB01 = {0.f,0.f}, hB23 = {0.f,0.f}, hB45 = {0.f,0.f}, hB67 = {0.f,0.f};
    const uint4* cp = (const uint4*)(csr_col + s);
    for (int base = 0; base < maxlen; base += 16) {
        GATHER16_U4(cp, xs_in, el, base, len)
    }

    int rs = ((threadIdx.x >> 6) << 3) + e;
    float y0, y1, y2, y3, y4;
    int c0 = el, c1 = el + 8, c2 = el + 16, c3 = el + 24, c4 = el + 32;
    {
        v2f h01 = hA01 + hB01, h23 = hA23 + hB23;
        v2f h45 = hA45 + hB45, h67 = hA67 + hB67;
        uint4 us = valid ? xs_in[r * 8 + el] : make_uint4(0u, 0u, 0u, 0u);
        acc2p(us.x, h01); acc2p(us.y, h23); acc2p(us.z, h45); acc2p(us.w, h67);
        float dr = valid ? dis[r] : 0.f;

        // per-wave transpose: same-wave produce->consume via LDS (lockstep;
        // compiler orders may-alias LDS ops) -- no barrier needed.
        *(float4*)&hl[rs][el * 8] =
            make_float4(h01.x * dr, h01.y * dr, h23.x * dr, h23.y * dr);
        *(float4*)&hl[rs][el * 8 + 4] =
            make_float4(h45.x * dr, h45.y * dr, h67.x * dr, h67.y * dr);

        y0 = bl[c0]; y1 = bl[c1]; y2 = bl[c2]; y3 = bl[c3]; y4 = bl[c4];
#pragma unroll
        for (int g = 0; g < 16; g++) {
            float4 hv = *(const float4*)&hl[rs][g * 4];   // broadcast per group
            float4 w0 = *(const float4*)&Wt[c0][g * 4];
            float4 w1 = *(const float4*)&Wt[c1][g * 4];
            float4 w2 = *(const float4*)&Wt[c2][g * 4];
            float4 w3 = *(const float4*)&Wt[c3][g * 4];
            float4 w4 = *(const float4*)&Wt[c4][g * 4];
            y0 += hv.x * w0.x + hv.y * w0.y + hv.z * w0.z + hv.w * w0.w;
            y1 += hv.x * w1.x + hv.y * w1.y + hv.z * w1.z + hv.w * w1.w;
            y2 += hv.x * w2.x + hv.y * w2.y + hv.z * w2.z + hv.w * w2.w;
            y3 += hv.x * w3.x + hv.y * w3.y + hv.z * w3.z + hv.w * w3.w;
            y4 += hv.x * w4.x + hv.y * w4.y + hv.z * w4.z + hv.w * w4.w;
        }
    }

    float m = fmaxf(fmaxf(fmaxf(y0, y1), fmaxf(y2, y3)), y4);
#pragma unroll
    for (int o = 4; o > 0; o >>= 1) m = fmaxf(m, __shfl_xor(m, o, 64));
    float sm = __expf(y0 - m) + __expf(y1 - m) + __expf(y2 - m) +
               __expf(y3 - m) + __expf(y4 - m);
#pragma unroll
    for (int o = 4; o > 0; o >>= 1) sm += __shfl_xor(sm, o, 64);
    float lse = m + __logf(sm);

    if (valid) {
        float* op = out + (long long)r * NCLS;
        op[c0] = y0 - lse;
        op[c1] = y1 - lse;
        op[c2] = y2 - lse;
        op[c3] = y3 - lse;
        op[c4] = y4 - lse;
    }
}

extern "C" void kernel_launch(void* const* d_in, const int* in_sizes, int n_in,
                              void* d_out, int out_size, void* d_ws, size_t ws_size,
                              hipStream_t stream) {
    const float* x  = (const float*)d_in[0];
    const int*   ei = (const int*)d_in[1];   // [2, E] flat: rows then cols (int32)
    const float* W  = (const float*)d_in[2]; // [64, 40]
    const float* b  = (const float*)d_in[3]; // [40]
    float* out = (float*)d_out;

    const int n = in_sizes[0] / D_FEAT;      // 100000
    const int e = in_sizes[1] / 2;           // 1600000
    const int nb = (n + BROWS - 1) / BROWS;  // 196

    const int* rows = ei;
    const int* cols = ei + e;

    // ws layout (int units, segments aligned):
    //   bucket_cursor[nb] | dis[n] | row_info[n] (uint2) | perm[nb*512] |
    //   bins[nb*BINCAP] | csr_col[nb*CSRCAP] | xs0 | xs1       (~45 MB)
    size_t na = ((size_t)n + 256) & ~(size_t)255;
    size_t npm = (size_t)nb * BROWS;         // multiple of 512
    int*      bucket_cursor = (int*)d_ws;
    float*    dis           = (float*)(bucket_cursor + 256);
    uint2*    row_info      = (uint2*)(dis + na);
    int*      perm          = (int*)(row_info + na);
    unsigned* bins          = (unsigned*)(perm + npm);
    int*      csr_col       = (int*)(bins + (size_t)nb * BINCAP);
    unsigned* xs0           = (unsigned*)(csr_col + (size_t)nb * CSRCAP);
    unsigned* xs1           = xs0 + (size_t)(n + 1) * (D_FEAT / 2);

    const int BS = 256;

    hipMemsetAsync(bucket_cursor, 0, (size_t)nb * sizeof(int), stream);
    {
        int blocks = (e + BS * EPT - 1) / (BS * EPT);  // 250
        bin_edges_kernel<<<blocks, BS, 0, stream>>>(rows, cols, bucket_cursor, bins, e, nb);
    }
    build_csr_kernel<<<nb, 512, 0, stream>>>(bins, bucket_cursor, csr_col, row_info, dis,
                                             perm, n);
    {
        int nwv = (n + 1) / 2;                           // sort: 2 rows per wave
        int sortBlocks = (nwv * 64 + BS - 1) / BS;
        int tot = (n + 1) * (D_FEAT / 2);
        int scaleBlocks = (tot + BS - 1) / BS;
        sort_scale_kernel<<<sortBlocks + scaleBlocks, BS, 0, stream>>>(
            csr_col, row_info, x, dis, xs0, xs1, n, sortBlocks);
    }

    int nperm = (int)npm;                    // nb*512 perm slots
    int nwaves = nperm / 8;                  // 8 rows per wave
    int blocks = (nwaves * 64 + BS - 1) / BS;
    spmm_hop1_kernel<<<blocks, BS, 0, stream>>>((const uint4*)xs0, (uint4*)xs1, perm,
                                                row_info, csr_col, dis, n, nperm);
    spmm_logits_kernel<<<blocks, BS, 0, stream>>>((const uint4*)xs1, perm, row_info, csr_col,
                                                  dis, W, b, out, n, nperm);
}